// Round 12
// baseline (248.517 us; speedup 1.0000x reference)
//
#include <hip/hip_runtime.h>
#include <hip/hip_bf16.h>

typedef __attribute__((ext_vector_type(8))) short short8;
typedef __attribute__((ext_vector_type(4))) float f32x4;
typedef float f32x4u __attribute__((ext_vector_type(4), aligned(4)));  // 4B-aligned dwordx4

constexpr int Bn = 2, Hn = 8, NQ = 2048, NK = 4096, Dd = 128, Wt = 127;
constexpr int QT = 64, KT = 64;
constexpr int SPLITS = 8, K1_TILES = 8, NC2 = 8;
constexpr int NROWS = Bn * Hn * NQ;  // 32768
constexpr float SCALE = 0.08838834764831845f;   // 1/sqrt(128)
constexpr float LOG2E = 1.4426950408889634f;
constexpr float S2 = SCALE * LOG2E;             // folded into the per-element FMA
constexpr float BSHIFT = 12.0f * LOG2E;         // fixed softmax shift, log2 units

// workspace layout (bytes)
constexpr size_t WS_SUMS = 0;                                   // 1 MB
constexpr size_t WS_K = 1u << 20;                               // 16 MB bf16 K
constexpr size_t WS_Q = WS_K + (size_t)Bn * Hn * NK * Dd * 2;   // 8 MB bf16 Q
constexpr size_t WS_B = WS_Q + (size_t)Bn * Hn * NQ * Dd * 2;   // 516 KB bias2

constexpr int KELEM = Bn * Hn * NK * Dd;  // 8388608
constexpr int QELEM = Bn * Hn * NQ * Dd;  // 4194304
constexpr int BELEM = Hn * Wt * Wt;       // 129032
constexpr int KBLK = KELEM / 2048;        // 4096
constexpr int QBLK = QELEM / 2048;        // 2048
constexpr int BBLK = (BELEM + 2047) / 2048;  // 64

__device__ __forceinline__ short bf16r(float f) {
  union { float f; unsigned u; } v; v.f = f;
  unsigned r = v.u + 0x7fffu + ((v.u >> 16) & 1u);
  return (short)(r >> 16);
}

__device__ __forceinline__ float exp2hw(float x) {
  float r;
  asm("v_exp_f32 %0, %1" : "=v"(r) : "v"(x));
  return r;
}

// ---------------- prepass: K,Q -> bf16; bias -> bias*log2e - BSHIFT ----------------
__global__ __launch_bounds__(256)
void prep_kernel(const float* __restrict__ Km, const float* __restrict__ Qm,
                 const float* __restrict__ Bias, short* __restrict__ wsK,
                 short* __restrict__ wsQ, float* __restrict__ wsB) {
  const int bid = blockIdx.x, tid = threadIdx.x;
  if (bid < KBLK) {
    size_t i = (size_t)bid * 2048 + tid * 8;
    float4 f0 = *(const float4*)(Km + i);
    float4 f1 = *(const float4*)(Km + i + 4);
    short8 v;
    v[0] = bf16r(f0.x); v[1] = bf16r(f0.y); v[2] = bf16r(f0.z); v[3] = bf16r(f0.w);
    v[4] = bf16r(f1.x); v[5] = bf16r(f1.y); v[6] = bf16r(f1.z); v[7] = bf16r(f1.w);
    *(short8*)(wsK + i) = v;
  } else if (bid < KBLK + QBLK) {
    size_t i = (size_t)(bid - KBLK) * 2048 + tid * 8;
    float4 f0 = *(const float4*)(Qm + i);
    float4 f1 = *(const float4*)(Qm + i + 4);
    short8 v;
    v[0] = bf16r(f0.x); v[1] = bf16r(f0.y); v[2] = bf16r(f0.z); v[3] = bf16r(f0.w);
    v[4] = bf16r(f1.x); v[5] = bf16r(f1.y); v[6] = bf16r(f1.z); v[7] = bf16r(f1.w);
    *(short8*)(wsQ + i) = v;
  } else {
    int i = (bid - KBLK - QBLK) * 2048 + tid * 8;
#pragma unroll
    for (int j = 0; j < 8; j++)
      if (i + j < BELEM) wsB[i + j] = Bias[i + j] * LOG2E - BSHIFT;
  }
}

// Stage one 64x128 bf16 K-tile into LDS via global_load_lds (linear dest,
// inverse-swizzled source — rule #21).
__device__ __forceinline__ void stage_async(int tid, const short* __restrict__ kp,
                                            int kt0, short* buf) {
  const int wave = tid >> 6, lane = tid & 63;
#pragma unroll
  for (int c = 0; c < 4; c++) {
    const int db = c * 4096 + wave * 1024 + lane * 16;  // dest byte (linear)
    const int row = db >> 8;
    const int scol = ((db >> 4) & 15) ^ (row & 7);      // inverse swizzle on source
    const short* src = kp + (size_t)(kt0 + row) * Dd + scol * 8;
    __builtin_amdgcn_global_load_lds(
        (const __attribute__((address_space(1))) void*)src,
        (__attribute__((address_space(3))) void*)(buf + ((c * 4096 + wave * 1024) >> 1)),
        16, 0, 0);
  }
}

// swizzled read: logical (krow, col16 = kc*4+g)
__device__ __forceinline__ short8 loadKfrag(const short* buf, int f, int kc,
                                            int l15, int g) {
  const int krow = f * 16 + l15;
  const int byte = (krow << 8) + ((((kc << 2) + g) ^ (krow & 7)) << 4);
  return *(const short8*)((const char*)buf + byte);
}

// ---------------- kernel 1: per-row partial denominators ----------------
__global__ __launch_bounds__(256, 5)  // 5 blocks/CU: LDS 5*32KB = 160KB exact fit
void rga_sum_kernel(const short* __restrict__ wsK, const short* __restrict__ wsQ,
                    const int* __restrict__ Pos, const float* __restrict__ wsB,
                    float* __restrict__ sums) {
  __shared__ short lds[2][KT * Dd];
  const int tid = threadIdx.x, wave = tid >> 6, lane = tid & 63;
  const int l15 = lane & 15, g = lane >> 4;
  const int x0 = blockIdx.x;
  const int x = (x0 & 7) * 512 + (x0 >> 3);  // XCD-bijective swizzle (4096 % 8 == 0)
  const int qt = x & 31, split = (x >> 5) & 7, bh = x >> 8;
  const int b = bh >> 3, h = bh & 7;

  const short* kp = wsK + (size_t)bh * NK * Dd;
  const short* qp = wsQ + (size_t)bh * NQ * Dd;
  const float* bp = wsB + (size_t)h * Wt * Wt;

  const int q = qt * QT + wave * 16 + l15;
  short8 qfrag[4];
#pragma unroll
  for (int kc = 0; kc < 4; kc++)
    qfrag[kc] = *(const short8*)(qp + (size_t)q * Dd + kc * 32 + g * 8);
  const int pxo = 63 - Pos[((size_t)b * NQ + q) * 2 + 0];
  const int pyo = 63 - Pos[((size_t)b * NQ + q) * 2 + 1];

  const int kt0 = split * (NK / SPLITS);
  stage_async(tid, kp, kt0, lds[0]);
  asm volatile("s_waitcnt vmcnt(0)" ::: "memory");
  __builtin_amdgcn_s_barrier();
  __builtin_amdgcn_sched_barrier(0);

  float ksum = 0.f;
  for (int t = 0; t < K1_TILES; t++) {
    const int kt = kt0 + t * KT;
    if (t + 1 < K1_TILES) stage_async(tid, kp, kt + KT, lds[(t + 1) & 1]);
    __builtin_amdgcn_sched_barrier(0);
    const short* buf = lds[t & 1];
    // one dwordx4 per f instead of 4 scalar loads: 4 VMEM instrs/wave-tile
    const float* brow = bp + ((kt >> 6) + pyo) * Wt + pxo + g * 4;
#pragma unroll
    for (int f = 0; f < 4; f++) {
      f32x4 acc = {0.f, 0.f, 0.f, 0.f};
#pragma unroll
      for (int kc = 0; kc < 4; kc++)
        acc = __builtin_amdgcn_mfma_f32_16x16x32_bf16(loadKfrag(buf, f, kc, l15, g),
                                                      qfrag[kc], acc, 0, 0, 0);
      const f32x4u bv = *(const f32x4u*)(brow + f * 16);
#pragma unroll
      for (int j = 0; j < 4; j++)
        ksum += exp2hw(acc[j] * S2 + bv[j]);
    }
    // raw barrier: no vmcnt(0) drain. stage(t+1) completion is implied by the
    // in-order vmcnt wait the compiler emits for this tile's bias loads
    // (issued after stage(t+1); vmcnt retires in order — m135).
    __builtin_amdgcn_s_barrier();
    __builtin_amdgcn_sched_barrier(0);
  }
  ksum += __shfl_xor(ksum, 16, 64);
  ksum += __shfl_xor(ksum, 32, 64);
  if (lane < 16) sums[(size_t)split * NROWS + (size_t)bh * NQ + q] = ksum;
}

// ---------------- kernel 2: recompute, normalize, write ----------------
__global__ __launch_bounds__(256, 5)  // 5 blocks/CU, 20 waves/CU
void rga_out_kernel(const short* __restrict__ wsK, const short* __restrict__ wsQ,
                    const int* __restrict__ Pos, const float* __restrict__ wsB,
                    const float* __restrict__ sums, float* __restrict__ Out) {
  __shared__ short lds[2][KT * Dd];
  const int tid = threadIdx.x, wave = tid >> 6, lane = tid & 63;
  const int l15 = lane & 15, g = lane >> 4;
  const int x0 = blockIdx.x;
  const int x = (x0 & 7) * 512 + (x0 >> 3);  // XCD-bijective swizzle (4096 % 8 == 0)
  const int qt = x & 31, kc8 = (x >> 5) & 7, bh = x >> 8;
  const int b = bh >> 3, h = bh & 7;

  const short* kp = wsK + (size_t)bh * NK * Dd;
  const short* qp = wsQ + (size_t)bh * NQ * Dd;
  const float* bp = wsB + (size_t)h * Wt * Wt;

  const int q = qt * QT + wave * 16 + l15;
  short8 qfrag[4];
#pragma unroll
  for (int kc = 0; kc < 4; kc++)
    qfrag[kc] = *(const short8*)(qp + (size_t)q * Dd + kc * 32 + g * 8);
  const int pxo = 63 - Pos[((size_t)b * NQ + q) * 2 + 0];
  const int pyo = 63 - Pos[((size_t)b * NQ + q) * 2 + 1];

  float lsum = 0.f;
#pragma unroll
  for (int s = 0; s < SPLITS; s++) lsum += sums[(size_t)s * NROWS + (size_t)bh * NQ + q];
  const float rl = 1.0f / lsum;

  float* orow = Out + ((size_t)bh * NQ + q) * NK;
  const int kbase = kc8 * (KT * NC2);
  stage_async(tid, kp, kbase, lds[0]);
  asm volatile("s_waitcnt vmcnt(0)" ::: "memory");
  __builtin_amdgcn_s_barrier();
  __builtin_amdgcn_sched_barrier(0);

  for (int t = 0; t < NC2; t++) {
    const int kt = kbase + t * KT;
    if (t + 1 < NC2) stage_async(tid, kp, kt + KT, lds[(t + 1) & 1]);
    __builtin_amdgcn_sched_barrier(0);
    const short* buf = lds[t & 1];
    const float* brow = bp + ((kt >> 6) + pyo) * Wt + pxo + g * 4;
#pragma unroll
    for (int f = 0; f < 4; f++) {
      f32x4 acc = {0.f, 0.f, 0.f, 0.f};
#pragma unroll
      for (int kc = 0; kc < 4; kc++)
        acc = __builtin_amdgcn_mfma_f32_16x16x32_bf16(loadKfrag(buf, f, kc, l15, g),
                                                      qfrag[kc], acc, 0, 0, 0);
      const int gx0 = f * 16 + g * 4;
      const f32x4u bv = *(const f32x4u*)(brow + f * 16);
      f32x4 v;
      v[0] = exp2hw(acc[0] * S2 + bv[0]) * rl;
      v[1] = exp2hw(acc[1] * S2 + bv[1]) * rl;
      v[2] = exp2hw(acc[2] * S2 + bv[2]) * rl;
      v[3] = exp2hw(acc[3] * S2 + bv[3]) * rl;
      // A/B vs r11: plain store through L2 (NT 64B segments may have caused
      // partial-line HBM writes; L2 merges adjacent 64B halves into full lines)
      *(f32x4*)(orow + kt + gx0) = v;
    }
    // raw barrier, no store drain.
    __builtin_amdgcn_s_barrier();
    __builtin_amdgcn_sched_barrier(0);
  }
}

extern "C" void kernel_launch(void* const* d_in, const int* in_sizes, int n_in,
                              void* d_out, int out_size, void* d_ws, size_t ws_size,
                              hipStream_t stream) {
  const float* q = (const float*)d_in[0];
  const float* k = (const float*)d_in[1];
  const int* pos = (const int*)d_in[2];
  const float* bias = (const float*)d_in[3];
  float* out = (float*)d_out;

  char* wsc = (char*)d_ws;
  float* sums = (float*)(wsc + WS_SUMS);
  short* wsK = (short*)(wsc + WS_K);
  short* wsQ = (short*)(wsc + WS_Q);
  float* wsB = (float*)(wsc + WS_B);

  hipLaunchKernelGGL(prep_kernel, dim3(KBLK + QBLK + BBLK), dim3(256), 0, stream,
                     k, q, bias, wsK, wsQ, wsB);
  // k1: 16 bh * 32 q-tiles * 8 splits = 4096 blocks
  hipLaunchKernelGGL(rga_sum_kernel, dim3(Bn * Hn * 32 * SPLITS), dim3(256), 0,
                     stream, wsK, wsQ, pos, wsB, sums);
  // k2: 16 bh * 32 q-tiles * 8 k-units(512) = 4096 blocks
  hipLaunchKernelGGL(rga_out_kernel, dim3(Bn * Hn * 32 * (NK / (KT * NC2))),
                     dim3(256), 0, stream, wsK, wsQ, pos, wsB, sums, out);
}

// Round 13
// 247.377 us; speedup vs baseline: 1.0046x; 1.0046x over previous
//
#include <hip/hip_runtime.h>
#include <hip/hip_bf16.h>

typedef __attribute__((ext_vector_type(8))) short short8;
typedef __attribute__((ext_vector_type(4))) float f32x4;
typedef float f32x4u __attribute__((ext_vector_type(4), aligned(4)));  // 4B-aligned dwordx4

constexpr int Bn = 2, Hn = 8, NQ = 2048, NK = 4096, Dd = 128, Wt = 127;
constexpr int QT = 64, KT = 64;
constexpr int SPLITS = 8, K1_TILES = 8, NC2 = 8;
constexpr int NROWS = Bn * Hn * NQ;  // 32768
constexpr float SCALE = 0.08838834764831845f;   // 1/sqrt(128)
constexpr float LOG2E = 1.4426950408889634f;
constexpr float S2 = SCALE * LOG2E;             // folded into the per-element FMA
constexpr float BSHIFT = 12.0f * LOG2E;         // fixed softmax shift, log2 units

// workspace layout (bytes)
constexpr size_t WS_SUMS = 0;                                   // 1 MB
constexpr size_t WS_K = 1u << 20;                               // 16 MB bf16 K
constexpr size_t WS_Q = WS_K + (size_t)Bn * Hn * NK * Dd * 2;   // 8 MB bf16 Q
constexpr size_t WS_B = WS_Q + (size_t)Bn * Hn * NQ * Dd * 2;   // 516 KB bias2

constexpr int KELEM = Bn * Hn * NK * Dd;  // 8388608
constexpr int QELEM = Bn * Hn * NQ * Dd;  // 4194304
constexpr int BELEM = Hn * Wt * Wt;       // 129032
constexpr int KBLK = KELEM / 2048;        // 4096
constexpr int QBLK = QELEM / 2048;        // 2048
constexpr int BBLK = (BELEM + 2047) / 2048;  // 64

__device__ __forceinline__ short bf16r(float f) {
  union { float f; unsigned u; } v; v.f = f;
  unsigned r = v.u + 0x7fffu + ((v.u >> 16) & 1u);
  return (short)(r >> 16);
}

__device__ __forceinline__ float exp2hw(float x) {
  float r;
  asm("v_exp_f32 %0, %1" : "=v"(r) : "v"(x));
  return r;
}

// ---------------- prepass: K,Q -> bf16; bias -> bias*log2e - BSHIFT ----------------
__global__ __launch_bounds__(256)
void prep_kernel(const float* __restrict__ Km, const float* __restrict__ Qm,
                 const float* __restrict__ Bias, short* __restrict__ wsK,
                 short* __restrict__ wsQ, float* __restrict__ wsB) {
  const int bid = blockIdx.x, tid = threadIdx.x;
  if (bid < KBLK) {
    size_t i = (size_t)bid * 2048 + tid * 8;
    float4 f0 = *(const float4*)(Km + i);
    float4 f1 = *(const float4*)(Km + i + 4);
    short8 v;
    v[0] = bf16r(f0.x); v[1] = bf16r(f0.y); v[2] = bf16r(f0.z); v[3] = bf16r(f0.w);
    v[4] = bf16r(f1.x); v[5] = bf16r(f1.y); v[6] = bf16r(f1.z); v[7] = bf16r(f1.w);
    *(short8*)(wsK + i) = v;
  } else if (bid < KBLK + QBLK) {
    size_t i = (size_t)(bid - KBLK) * 2048 + tid * 8;
    float4 f0 = *(const float4*)(Qm + i);
    float4 f1 = *(const float4*)(Qm + i + 4);
    short8 v;
    v[0] = bf16r(f0.x); v[1] = bf16r(f0.y); v[2] = bf16r(f0.z); v[3] = bf16r(f0.w);
    v[4] = bf16r(f1.x); v[5] = bf16r(f1.y); v[6] = bf16r(f1.z); v[7] = bf16r(f1.w);
    *(short8*)(wsQ + i) = v;
  } else {
    int i = (bid - KBLK - QBLK) * 2048 + tid * 8;
#pragma unroll
    for (int j = 0; j < 8; j++)
      if (i + j < BELEM) wsB[i + j] = Bias[i + j] * LOG2E - BSHIFT;
  }
}

// Stage one 64x128 bf16 K-tile into LDS via global_load_lds (linear dest,
// inverse-swizzled source — rule #21).
__device__ __forceinline__ void stage_async(int tid, const short* __restrict__ kp,
                                            int kt0, short* buf) {
  const int wave = tid >> 6, lane = tid & 63;
#pragma unroll
  for (int c = 0; c < 4; c++) {
    const int db = c * 4096 + wave * 1024 + lane * 16;  // dest byte (linear)
    const int row = db >> 8;
    const int scol = ((db >> 4) & 15) ^ (row & 7);      // inverse swizzle on source
    const short* src = kp + (size_t)(kt0 + row) * Dd + scol * 8;
    __builtin_amdgcn_global_load_lds(
        (const __attribute__((address_space(1))) void*)src,
        (__attribute__((address_space(3))) void*)(buf + ((c * 4096 + wave * 1024) >> 1)),
        16, 0, 0);
  }
}

// swizzled read: logical (krow, col16 = kc*4+g)
__device__ __forceinline__ short8 loadKfrag(const short* buf, int f, int kc,
                                            int l15, int g) {
  const int krow = f * 16 + l15;
  const int byte = (krow << 8) + ((((kc << 2) + g) ^ (krow & 7)) << 4);
  return *(const short8*)((const char*)buf + byte);
}

// ---------------- kernel 1: per-row partial denominators ----------------
__global__ __launch_bounds__(256, 5)  // 5 blocks/CU: LDS 5*32KB = 160KB exact fit
void rga_sum_kernel(const short* __restrict__ wsK, const short* __restrict__ wsQ,
                    const int* __restrict__ Pos, const float* __restrict__ wsB,
                    float* __restrict__ sums) {
  __shared__ short lds[2][KT * Dd];
  const int tid = threadIdx.x, wave = tid >> 6, lane = tid & 63;
  const int l15 = lane & 15, g = lane >> 4;
  const int x0 = blockIdx.x;
  const int x = (x0 & 7) * 512 + (x0 >> 3);  // XCD-bijective swizzle (4096 % 8 == 0)
  const int qt = x & 31, split = (x >> 5) & 7, bh = x >> 8;
  const int b = bh >> 3, h = bh & 7;

  const short* kp = wsK + (size_t)bh * NK * Dd;
  const short* qp = wsQ + (size_t)bh * NQ * Dd;
  const float* bp = wsB + (size_t)h * Wt * Wt;

  const int q = qt * QT + wave * 16 + l15;
  short8 qfrag[4];
#pragma unroll
  for (int kc = 0; kc < 4; kc++)
    qfrag[kc] = *(const short8*)(qp + (size_t)q * Dd + kc * 32 + g * 8);
  const int pxo = 63 - Pos[((size_t)b * NQ + q) * 2 + 0];
  const int pyo = 63 - Pos[((size_t)b * NQ + q) * 2 + 1];

  const int kt0 = split * (NK / SPLITS);
  stage_async(tid, kp, kt0, lds[0]);
  asm volatile("s_waitcnt vmcnt(0)" ::: "memory");
  __builtin_amdgcn_s_barrier();
  __builtin_amdgcn_sched_barrier(0);

  float ksum = 0.f;
  for (int t = 0; t < K1_TILES; t++) {
    const int kt = kt0 + t * KT;
    if (t + 1 < K1_TILES) stage_async(tid, kp, kt + KT, lds[(t + 1) & 1]);
    // batch all 4 bias dwordx4 loads upfront: 4 loads in flight, latency
    // hidden under the 16-MFMA cluster (instead of per-f serialization)
    const float* brow = bp + ((kt >> 6) + pyo) * Wt + pxo + g * 4;
    f32x4u bv[4];
#pragma unroll
    for (int f = 0; f < 4; f++) bv[f] = *(const f32x4u*)(brow + f * 16);
    __builtin_amdgcn_sched_barrier(0);
    const short* buf = lds[t & 1];
    __builtin_amdgcn_s_setprio(1);
#pragma unroll
    for (int f = 0; f < 4; f++) {
      f32x4 acc = {0.f, 0.f, 0.f, 0.f};
#pragma unroll
      for (int kc = 0; kc < 4; kc++)
        acc = __builtin_amdgcn_mfma_f32_16x16x32_bf16(loadKfrag(buf, f, kc, l15, g),
                                                      qfrag[kc], acc, 0, 0, 0);
#pragma unroll
      for (int j = 0; j < 4; j++)
        ksum += exp2hw(acc[j] * S2 + bv[f][j]);
    }
    __builtin_amdgcn_s_setprio(0);
    // raw barrier: no vmcnt(0) drain. stage(t+1) completion is implied by the
    // in-order vmcnt wait the compiler emits for this tile's bias loads
    // (issued after stage(t+1); vmcnt retires in order — m135).
    __builtin_amdgcn_s_barrier();
    __builtin_amdgcn_sched_barrier(0);
  }
  ksum += __shfl_xor(ksum, 16, 64);
  ksum += __shfl_xor(ksum, 32, 64);
  if (lane < 16) sums[(size_t)split * NROWS + (size_t)bh * NQ + q] = ksum;
}

// ---------------- kernel 2: recompute, normalize, write ----------------
__global__ __launch_bounds__(256, 5)  // 5 blocks/CU, 20 waves/CU
void rga_out_kernel(const short* __restrict__ wsK, const short* __restrict__ wsQ,
                    const int* __restrict__ Pos, const float* __restrict__ wsB,
                    const float* __restrict__ sums, float* __restrict__ Out) {
  __shared__ short lds[2][KT * Dd];
  const int tid = threadIdx.x, wave = tid >> 6, lane = tid & 63;
  const int l15 = lane & 15, g = lane >> 4;
  const int x0 = blockIdx.x;
  const int x = (x0 & 7) * 512 + (x0 >> 3);  // XCD-bijective swizzle (4096 % 8 == 0)
  const int qt = x & 31, kc8 = (x >> 5) & 7, bh = x >> 8;
  const int b = bh >> 3, h = bh & 7;

  const short* kp = wsK + (size_t)bh * NK * Dd;
  const short* qp = wsQ + (size_t)bh * NQ * Dd;
  const float* bp = wsB + (size_t)h * Wt * Wt;

  const int q = qt * QT + wave * 16 + l15;
  short8 qfrag[4];
#pragma unroll
  for (int kc = 0; kc < 4; kc++)
    qfrag[kc] = *(const short8*)(qp + (size_t)q * Dd + kc * 32 + g * 8);
  const int pxo = 63 - Pos[((size_t)b * NQ + q) * 2 + 0];
  const int pyo = 63 - Pos[((size_t)b * NQ + q) * 2 + 1];

  float lsum = 0.f;
#pragma unroll
  for (int s = 0; s < SPLITS; s++) lsum += sums[(size_t)s * NROWS + (size_t)bh * NQ + q];
  const float rl = 1.0f / lsum;

  float* orow = Out + ((size_t)bh * NQ + q) * NK;
  const int kbase = kc8 * (KT * NC2);
  stage_async(tid, kp, kbase, lds[0]);
  asm volatile("s_waitcnt vmcnt(0)" ::: "memory");
  __builtin_amdgcn_s_barrier();
  __builtin_amdgcn_sched_barrier(0);

  for (int t = 0; t < NC2; t++) {
    const int kt = kbase + t * KT;
    if (t + 1 < NC2) stage_async(tid, kp, kt + KT, lds[(t + 1) & 1]);
    const float* brow = bp + ((kt >> 6) + pyo) * Wt + pxo + g * 4;
    f32x4u bv[4];
#pragma unroll
    for (int f = 0; f < 4; f++) bv[f] = *(const f32x4u*)(brow + f * 16);
    __builtin_amdgcn_sched_barrier(0);
    const short* buf = lds[t & 1];
    __builtin_amdgcn_s_setprio(1);
#pragma unroll
    for (int f = 0; f < 4; f++) {
      f32x4 acc = {0.f, 0.f, 0.f, 0.f};
#pragma unroll
      for (int kc = 0; kc < 4; kc++)
        acc = __builtin_amdgcn_mfma_f32_16x16x32_bf16(loadKfrag(buf, f, kc, l15, g),
                                                      qfrag[kc], acc, 0, 0, 0);
      const int gx0 = f * 16 + g * 4;
      f32x4 v;
      v[0] = exp2hw(acc[0] * S2 + bv[f][0]) * rl;
      v[1] = exp2hw(acc[1] * S2 + bv[f][1]) * rl;
      v[2] = exp2hw(acc[2] * S2 + bv[f][2]) * rl;
      v[3] = exp2hw(acc[3] * S2 + bv[f][3]) * rl;
      __builtin_nontemporal_store(v, (f32x4*)(orow + kt + gx0));
    }
    __builtin_amdgcn_s_setprio(0);
    // raw barrier, no store drain (stores are vmcnt-tracked; __syncthreads'
    // vmcnt(0) would wait ~900cy of HBM store latency every tile).
    __builtin_amdgcn_s_barrier();
    __builtin_amdgcn_sched_barrier(0);
  }
}

extern "C" void kernel_launch(void* const* d_in, const int* in_sizes, int n_in,
                              void* d_out, int out_size, void* d_ws, size_t ws_size,
                              hipStream_t stream) {
  const float* q = (const float*)d_in[0];
  const float* k = (const float*)d_in[1];
  const int* pos = (const int*)d_in[2];
  const float* bias = (const float*)d_in[3];
  float* out = (float*)d_out;

  char* wsc = (char*)d_ws;
  float* sums = (float*)(wsc + WS_SUMS);
  short* wsK = (short*)(wsc + WS_K);
  short* wsQ = (short*)(wsc + WS_Q);
  float* wsB = (float*)(wsc + WS_B);

  hipLaunchKernelGGL(prep_kernel, dim3(KBLK + QBLK + BBLK), dim3(256), 0, stream,
                     k, q, bias, wsK, wsQ, wsB);
  // k1: 16 bh * 32 q-tiles * 8 splits = 4096 blocks
  hipLaunchKernelGGL(rga_sum_kernel, dim3(Bn * Hn * 32 * SPLITS), dim3(256), 0,
                     stream, wsK, wsQ, pos, wsB, sums);
  // k2: 16 bh * 32 q-tiles * 8 k-units(512) = 4096 blocks
  hipLaunchKernelGGL(rga_out_kernel, dim3(Bn * Hn * 32 * (NK / (KT * NC2))),
                     dim3(256), 0, stream, wsK, wsQ, pos, wsB, sums, out);
}

// Round 14
// 209.586 us; speedup vs baseline: 1.1858x; 1.1803x over previous
//
#include <hip/hip_runtime.h>
#include <hip/hip_bf16.h>

typedef __attribute__((ext_vector_type(8))) short short8;
typedef __attribute__((ext_vector_type(4))) float f32x4;
typedef float f32x4u __attribute__((ext_vector_type(4), aligned(4)));  // 4B-aligned dwordx4

constexpr int Bn = 2, Hn = 8, NQ = 2048, NK = 4096, Dd = 128, Wt = 127;
constexpr int QT = 64, KT = 64;
constexpr int SPLITS = 8, K1_TILES = 8, NC2 = 8;
constexpr int NROWS = Bn * Hn * NQ;  // 32768
constexpr float SCALE = 0.08838834764831845f;   // 1/sqrt(128)
constexpr float LOG2E = 1.4426950408889634f;
constexpr float S2 = SCALE * LOG2E;             // folded into the per-element FMA
constexpr float BSHIFT = 12.0f * LOG2E;         // fixed softmax shift, log2 units

// workspace layout (bytes)
constexpr size_t WS_SUMS = 0;                                   // 1 MB
constexpr size_t WS_K = 1u << 20;                               // 16 MB bf16 K
constexpr size_t WS_Q = WS_K + (size_t)Bn * Hn * NK * Dd * 2;   // 8 MB bf16 Q
constexpr size_t WS_B = WS_Q + (size_t)Bn * Hn * NQ * Dd * 2;   // 516 KB bias2

constexpr int KELEM = Bn * Hn * NK * Dd;  // 8388608
constexpr int QELEM = Bn * Hn * NQ * Dd;  // 4194304
constexpr int BELEM = Hn * Wt * Wt;       // 129032
constexpr int KBLK = KELEM / 2048;        // 4096
constexpr int QBLK = QELEM / 2048;        // 2048
constexpr int BBLK = (BELEM + 2047) / 2048;  // 64

__device__ __forceinline__ short bf16r(float f) {
  union { float f; unsigned u; } v; v.f = f;
  unsigned r = v.u + 0x7fffu + ((v.u >> 16) & 1u);
  return (short)(r >> 16);
}

__device__ __forceinline__ float exp2hw(float x) {
  float r;
  asm("v_exp_f32 %0, %1" : "=v"(r) : "v"(x));
  return r;
}

// ---------------- prepass: K,Q -> bf16; bias -> bias*log2e - BSHIFT ----------------
__global__ __launch_bounds__(256)
void prep_kernel(const float* __restrict__ Km, const float* __restrict__ Qm,
                 const float* __restrict__ Bias, short* __restrict__ wsK,
                 short* __restrict__ wsQ, float* __restrict__ wsB) {
  const int bid = blockIdx.x, tid = threadIdx.x;
  if (bid < KBLK) {
    size_t i = (size_t)bid * 2048 + tid * 8;
    float4 f0 = *(const float4*)(Km + i);
    float4 f1 = *(const float4*)(Km + i + 4);
    short8 v;
    v[0] = bf16r(f0.x); v[1] = bf16r(f0.y); v[2] = bf16r(f0.z); v[3] = bf16r(f0.w);
    v[4] = bf16r(f1.x); v[5] = bf16r(f1.y); v[6] = bf16r(f1.z); v[7] = bf16r(f1.w);
    *(short8*)(wsK + i) = v;
  } else if (bid < KBLK + QBLK) {
    size_t i = (size_t)(bid - KBLK) * 2048 + tid * 8;
    float4 f0 = *(const float4*)(Qm + i);
    float4 f1 = *(const float4*)(Qm + i + 4);
    short8 v;
    v[0] = bf16r(f0.x); v[1] = bf16r(f0.y); v[2] = bf16r(f0.z); v[3] = bf16r(f0.w);
    v[4] = bf16r(f1.x); v[5] = bf16r(f1.y); v[6] = bf16r(f1.z); v[7] = bf16r(f1.w);
    *(short8*)(wsQ + i) = v;
  } else {
    int i = (bid - KBLK - QBLK) * 2048 + tid * 8;
#pragma unroll
    for (int j = 0; j < 8; j++)
      if (i + j < BELEM) wsB[i + j] = Bias[i + j] * LOG2E - BSHIFT;
  }
}

// Stage one 64x128 bf16 K-tile into LDS via global_load_lds (linear dest,
// inverse-swizzled source — rule #21).
__device__ __forceinline__ void stage_async(int tid, const short* __restrict__ kp,
                                            int kt0, short* buf) {
  const int wave = tid >> 6, lane = tid & 63;
#pragma unroll
  for (int c = 0; c < 4; c++) {
    const int db = c * 4096 + wave * 1024 + lane * 16;  // dest byte (linear)
    const int row = db >> 8;
    const int scol = ((db >> 4) & 15) ^ (row & 7);      // inverse swizzle on source
    const short* src = kp + (size_t)(kt0 + row) * Dd + scol * 8;
    __builtin_amdgcn_global_load_lds(
        (const __attribute__((address_space(1))) void*)src,
        (__attribute__((address_space(3))) void*)(buf + ((c * 4096 + wave * 1024) >> 1)),
        16, 0, 0);
  }
}

// swizzled read: logical (krow, col16 = kc*4+g)
__device__ __forceinline__ short8 loadKfrag(const short* buf, int f, int kc,
                                            int l15, int g) {
  const int krow = f * 16 + l15;
  const int byte = (krow << 8) + ((((kc << 2) + g) ^ (krow & 7)) << 4);
  return *(const short8*)((const char*)buf + byte);
}

// ---------------- kernel 1: per-row partial denominators ----------------
__global__ __launch_bounds__(256, 5)  // 5 blocks/CU: LDS 5*32KB = 160KB exact fit
void rga_sum_kernel(const short* __restrict__ wsK, const short* __restrict__ wsQ,
                    const int* __restrict__ Pos, const float* __restrict__ wsB,
                    float* __restrict__ sums) {
  __shared__ short lds[2][KT * Dd];
  const int tid = threadIdx.x, wave = tid >> 6, lane = tid & 63;
  const int l15 = lane & 15, g = lane >> 4;
  const int x0 = blockIdx.x;
  const int x = (x0 & 7) * 512 + (x0 >> 3);  // XCD-bijective swizzle (4096 % 8 == 0)
  const int qt = x & 31, split = (x >> 5) & 7, bh = x >> 8;
  const int b = bh >> 3, h = bh & 7;

  const short* kp = wsK + (size_t)bh * NK * Dd;
  const short* qp = wsQ + (size_t)bh * NQ * Dd;
  const float* bp = wsB + (size_t)h * Wt * Wt;

  const int q = qt * QT + wave * 16 + l15;
  short8 qfrag[4];
#pragma unroll
  for (int kc = 0; kc < 4; kc++)
    qfrag[kc] = *(const short8*)(qp + (size_t)q * Dd + kc * 32 + g * 8);
  const int pxo = 63 - Pos[((size_t)b * NQ + q) * 2 + 0];
  const int pyo = 63 - Pos[((size_t)b * NQ + q) * 2 + 1];

  const int kt0 = split * (NK / SPLITS);
  stage_async(tid, kp, kt0, lds[0]);
  asm volatile("s_waitcnt vmcnt(0)" ::: "memory");
  __builtin_amdgcn_s_barrier();
  __builtin_amdgcn_sched_barrier(0);

  float ksum = 0.f;
  for (int t = 0; t < K1_TILES; t++) {
    const int kt = kt0 + t * KT;
    if (t + 1 < K1_TILES) stage_async(tid, kp, kt + KT, lds[(t + 1) & 1]);
    __builtin_amdgcn_sched_barrier(0);
    const short* buf = lds[t & 1];
    // one dwordx4 per f instead of 4 scalar loads: 4 VMEM instrs/wave-tile
    const float* brow = bp + ((kt >> 6) + pyo) * Wt + pxo + g * 4;
#pragma unroll
    for (int f = 0; f < 4; f++) {
      f32x4 acc = {0.f, 0.f, 0.f, 0.f};
#pragma unroll
      for (int kc = 0; kc < 4; kc++)
        acc = __builtin_amdgcn_mfma_f32_16x16x32_bf16(loadKfrag(buf, f, kc, l15, g),
                                                      qfrag[kc], acc, 0, 0, 0);
      const f32x4u bv = *(const f32x4u*)(brow + f * 16);
#pragma unroll
      for (int j = 0; j < 4; j++)
        ksum += exp2hw(acc[j] * S2 + bv[j]);
    }
    // raw barrier: no vmcnt(0) drain. stage(t+1) completion is implied by the
    // in-order vmcnt wait the compiler emits for this tile's bias loads
    // (issued after stage(t+1); vmcnt retires in order — m135).
    __builtin_amdgcn_s_barrier();
    __builtin_amdgcn_sched_barrier(0);
  }
  ksum += __shfl_xor(ksum, 16, 64);
  ksum += __shfl_xor(ksum, 32, 64);
  if (lane < 16) sums[(size_t)split * NROWS + (size_t)bh * NQ + q] = ksum;
}

// ---------------- kernel 2: recompute, normalize, write ----------------
__global__ __launch_bounds__(256, 5)  // 5 blocks/CU, 20 waves/CU
void rga_out_kernel(const short* __restrict__ wsK, const short* __restrict__ wsQ,
                    const int* __restrict__ Pos, const float* __restrict__ wsB,
                    const float* __restrict__ sums, float* __restrict__ Out) {
  __shared__ short lds[2][KT * Dd];
  const int tid = threadIdx.x, wave = tid >> 6, lane = tid & 63;
  const int l15 = lane & 15, g = lane >> 4;
  const int x0 = blockIdx.x;
  const int x = (x0 & 7) * 512 + (x0 >> 3);  // XCD-bijective swizzle (4096 % 8 == 0)
  const int qt = x & 31, kc8 = (x >> 5) & 7, bh = x >> 8;
  const int b = bh >> 3, h = bh & 7;

  const short* kp = wsK + (size_t)bh * NK * Dd;
  const short* qp = wsQ + (size_t)bh * NQ * Dd;
  const float* bp = wsB + (size_t)h * Wt * Wt;

  const int q = qt * QT + wave * 16 + l15;
  short8 qfrag[4];
#pragma unroll
  for (int kc = 0; kc < 4; kc++)
    qfrag[kc] = *(const short8*)(qp + (size_t)q * Dd + kc * 32 + g * 8);
  const int pxo = 63 - Pos[((size_t)b * NQ + q) * 2 + 0];
  const int pyo = 63 - Pos[((size_t)b * NQ + q) * 2 + 1];

  float lsum = 0.f;
#pragma unroll
  for (int s = 0; s < SPLITS; s++) lsum += sums[(size_t)s * NROWS + (size_t)bh * NQ + q];
  const float rl = 1.0f / lsum;

  float* orow = Out + ((size_t)bh * NQ + q) * NK;
  const int kbase = kc8 * (KT * NC2);
  stage_async(tid, kp, kbase, lds[0]);
  asm volatile("s_waitcnt vmcnt(0)" ::: "memory");
  __builtin_amdgcn_s_barrier();
  __builtin_amdgcn_sched_barrier(0);

  for (int t = 0; t < NC2; t++) {
    const int kt = kbase + t * KT;
    if (t + 1 < NC2) stage_async(tid, kp, kt + KT, lds[(t + 1) & 1]);
    __builtin_amdgcn_sched_barrier(0);
    const short* buf = lds[t & 1];
    const float* brow = bp + ((kt >> 6) + pyo) * Wt + pxo + g * 4;
#pragma unroll
    for (int f = 0; f < 4; f++) {
      f32x4 acc = {0.f, 0.f, 0.f, 0.f};
#pragma unroll
      for (int kc = 0; kc < 4; kc++)
        acc = __builtin_amdgcn_mfma_f32_16x16x32_bf16(loadKfrag(buf, f, kc, l15, g),
                                                      qfrag[kc], acc, 0, 0, 0);
      const int gx0 = f * 16 + g * 4;
      const f32x4u bv = *(const f32x4u*)(brow + f * 16);
      f32x4 v;
      v[0] = exp2hw(acc[0] * S2 + bv[0]) * rl;
      v[1] = exp2hw(acc[1] * S2 + bv[1]) * rl;
      v[2] = exp2hw(acc[2] * S2 + bv[2]) * rl;
      v[3] = exp2hw(acc[3] * S2 + bv[3]) * rl;
      __builtin_nontemporal_store(v, (f32x4*)(orow + kt + gx0));
    }
    // raw barrier, no store drain (stores are vmcnt-tracked; __syncthreads'
    // vmcnt(0) would wait ~900cy of HBM store latency every tile).
    __builtin_amdgcn_s_barrier();
    __builtin_amdgcn_sched_barrier(0);
  }
}

extern "C" void kernel_launch(void* const* d_in, const int* in_sizes, int n_in,
                              void* d_out, int out_size, void* d_ws, size_t ws_size,
                              hipStream_t stream) {
  const float* q = (const float*)d_in[0];
  const float* k = (const float*)d_in[1];
  const int* pos = (const int*)d_in[2];
  const float* bias = (const float*)d_in[3];
  float* out = (float*)d_out;

  char* wsc = (char*)d_ws;
  float* sums = (float*)(wsc + WS_SUMS);
  short* wsK = (short*)(wsc + WS_K);
  short* wsQ = (short*)(wsc + WS_Q);
  float* wsB = (float*)(wsc + WS_B);

  hipLaunchKernelGGL(prep_kernel, dim3(KBLK + QBLK + BBLK), dim3(256), 0, stream,
                     k, q, bias, wsK, wsQ, wsB);
  // k1: 16 bh * 32 q-tiles * 8 splits = 4096 blocks
  hipLaunchKernelGGL(rga_sum_kernel, dim3(Bn * Hn * 32 * SPLITS), dim3(256), 0,
                     stream, wsK, wsQ, pos, wsB, sums);
  // k2: 16 bh * 32 q-tiles * 8 k-units(512) = 4096 blocks
  hipLaunchKernelGGL(rga_out_kernel, dim3(Bn * Hn * 32 * (NK / (KT * NC2))),
                     dim3(256), 0, stream, wsK, wsQ, pos, wsB, sums, out);
}